// Round 1
// baseline (28584.381 us; speedup 1.0000x reference)
//
#include <hip/hip_runtime.h>

typedef unsigned short u16;
typedef unsigned int u32;
typedef __attribute__((ext_vector_type(8))) short bf16x8;
typedef __attribute__((ext_vector_type(4))) float f32x4;

#define S_LEN 5120
#define NB 16
#define UA 384
#define UB 64
#define GA 1152

__device__ __forceinline__ float bf2f(u16 u) { return __uint_as_float(((u32)u) << 16); }
__device__ __forceinline__ u16 f2bf(float f) {
    u32 x = __float_as_uint(f);
    return (u16)((x + 0x7fffu + ((x >> 16) & 1u)) >> 16);
}
__device__ __forceinline__ float blo(u32 w) { return __uint_as_float(w << 16); }
__device__ __forceinline__ float bhi(u32 w) { return __uint_as_float(w & 0xffff0000u); }
__device__ __forceinline__ float sigm(float x) { return 1.f / (1.f + __expf(-x)); }
__device__ __forceinline__ float tanh_(float x) { float e = __expf(2.f * x); return 1.f - 2.f / (e + 1.f); }
__device__ __forceinline__ uint2 pack4(float4 v) {
    return make_uint2((u32)f2bf(v.x) | ((u32)f2bf(v.y) << 16),
                      (u32)f2bf(v.z) | ((u32)f2bf(v.w) << 16));
}

// ---------------- convert grua_wih to bf16 ----------------
__global__ __launch_bounds__(256) void k_cvt(const float* __restrict__ src, u16* __restrict__ dst) {
    int i = blockIdx.x * 256 + threadIdx.x;
    dst[i] = f2bf(src[i]);
}

// ---------------- frame-rate network ----------------
__global__ __launch_bounds__(128) void k_frame1(const float* __restrict__ features, const int* __restrict__ periods,
                                                const float* __restrict__ pemb, const float* __restrict__ w,
                                                const float* __restrict__ bias, float* __restrict__ c1) {
    __shared__ float fin[3][84];
    int t = blockIdx.x, b = blockIdx.y, o = threadIdx.x;
    for (int i = threadIdx.x; i < 252; i += 128) {
        int kk = i / 84, ci = i % 84, tt = t + kk;
        float v;
        if (ci < 20) v = features[(b * 36 + tt) * 20 + ci];
        else v = pemb[periods[b * 36 + tt] * 64 + (ci - 20)];
        fin[kk][ci] = v;
    }
    __syncthreads();
    float acc = bias[o];
    for (int kk = 0; kk < 3; kk++)
        for (int ci = 0; ci < 84; ci++)
            acc = fmaf(fin[kk][ci], w[o * 252 + ci * 3 + kk], acc);
    c1[(b * 34 + t) * 128 + o] = tanh_(acc);
}

__global__ __launch_bounds__(128) void k_frame2(const float* __restrict__ c1, const float* __restrict__ w,
                                                const float* __restrict__ bias, float* __restrict__ c2) {
    __shared__ float fin[3][128];
    int t = blockIdx.x, b = blockIdx.y, o = threadIdx.x;
    for (int i = threadIdx.x; i < 384; i += 128) {
        int kk = i >> 7, ci = i & 127;
        fin[kk][ci] = c1[(b * 34 + t + kk) * 128 + ci];
    }
    __syncthreads();
    float acc = bias[o];
    for (int kk = 0; kk < 3; kk++)
        for (int ci = 0; ci < 128; ci++)
            acc = fmaf(fin[kk][ci], w[o * 384 + ci * 3 + kk], acc);
    c2[(b * 32 + t) * 128 + o] = tanh_(acc);
}

__global__ __launch_bounds__(128) void k_fd(const float* __restrict__ c2, const float* __restrict__ w1,
                                            const float* __restrict__ b1, const float* __restrict__ w2,
                                            const float* __restrict__ b2, float* __restrict__ cc) {
    __shared__ float a0[128], a1s[128];
    int t = blockIdx.x, b = blockIdx.y, o = threadIdx.x;
    a0[o] = c2[(b * 32 + t) * 128 + o];
    __syncthreads();
    float acc = b1[o];
    for (int k = 0; k < 128; k++) acc = fmaf(a0[k], w1[o * 128 + k], acc);
    a1s[o] = tanh_(acc);
    __syncthreads();
    float acc2 = b2[o];
    for (int k = 0; k < 128; k++) acc2 = fmaf(a1s[k], w2[o * 128 + k], acc2);
    cc[(b * 32 + t) * 128 + o] = tanh_(acc2);
}

// cpart[b][fr][192] = grub_wih[:,384:512] @ c[b][fr] + grub_bih
__global__ __launch_bounds__(192) void k_cpart(const float* __restrict__ cc, const float* __restrict__ wihB,
                                               const float* __restrict__ bihB, float* __restrict__ cpart) {
    __shared__ float cl[128];
    int fr = blockIdx.x, b = blockIdx.y, o = threadIdx.x;
    if (o < 128) cl[o] = cc[(b * 32 + fr) * 128 + o];
    __syncthreads();
    float acc = bihB[o];
    for (int k = 0; k < 128; k++) acc = fmaf(cl[k], wihB[o * 512 + 384 + k], acc);
    cpart[((size_t)b * 32 + fr) * 192 + o] = acc;
}

// ---------------- init ring buffers & flags ----------------
__global__ __launch_bounds__(1024) void k_init(const float* __restrict__ h0a, const float* __restrict__ h0b,
                                               float* hA, float* hB, u32* flags) {
    int gid = blockIdx.x * 1024 + threadIdx.x;
    if (gid < 256) { flags[gid] = 0; return; }
    int i = gid - 256;
    if (i < NB * UA) { int b = i / UA, u = i % UA; hA[((size_t)b * 8 + 7) * UA + u] = h0a[i]; return; }
    i -= NB * UA;
    if (i < NB * UB) { int b = i / UB, u = i % UB; hB[((size_t)b * 2 + 1) * UB + u] = h0b[i]; return; }
}

// ---------------- GRU-A input projection GEMM ----------------
// xp[81920][1152] = embed(X)[81920][512] @ wihA^T  + bih   (bf16 MFMA, bf16 out)
__global__ __launch_bounds__(256) void k_gemm(const int* __restrict__ signals, const float* __restrict__ semb,
                                              const float* __restrict__ c, const u16* __restrict__ wih,
                                              const float* __restrict__ bih, u16* __restrict__ xp) {
    __shared__ u16 As[64][40];
    __shared__ u16 Bs[64][40];
    int m0 = blockIdx.x * 64, n0 = blockIdx.y * 64;
    int tid = threadIdx.x;
    int r = tid >> 2, kc = tid & 3;
    int lane = tid & 63, wv = tid >> 6;
    int wr = wv >> 1, wc = wv & 1;
    int mrow = m0 + r;
    int b = mrow / S_LEN, s = mrow % S_LEN;
    const int* sigrow = signals + mrow * 3;
    const float* crow = c + ((size_t)(b * 32) + s / 160) * 128;
    f32x4 acc[2][2];
#pragma unroll
    for (int i = 0; i < 2; i++)
#pragma unroll
        for (int j = 0; j < 2; j++) { acc[i][j][0] = 0.f; acc[i][j][1] = 0.f; acc[i][j][2] = 0.f; acc[i][j][3] = 0.f; }
    for (int k0 = 0; k0 < 512; k0 += 32) {
        int k = k0 + kc * 8;
        float v[8];
        if (k < 384) {
            int idx = sigrow[k >> 7];
            const float* src = semb + idx * 128 + (k & 127);
#pragma unroll
            for (int j = 0; j < 8; j++) v[j] = src[j];
        } else {
            const float* src = crow + (k - 384);
#pragma unroll
            for (int j = 0; j < 8; j++) v[j] = src[j];
        }
        u32 pk[4];
#pragma unroll
        for (int j = 0; j < 4; j++) pk[j] = (u32)f2bf(v[2 * j]) | ((u32)f2bf(v[2 * j + 1]) << 16);
        *(uint4*)&As[r][kc * 8] = *(uint4*)pk;
        *(uint4*)&Bs[r][kc * 8] = *(const uint4*)&wih[(size_t)(n0 + r) * 512 + k];
        __syncthreads();
        bf16x8 af[2], bfr[2];
#pragma unroll
        for (int mi = 0; mi < 2; mi++) af[mi] = *(const bf16x8*)&As[wr * 32 + mi * 16 + (lane & 15)][(lane >> 4) * 8];
#pragma unroll
        for (int ni = 0; ni < 2; ni++) bfr[ni] = *(const bf16x8*)&Bs[wc * 32 + ni * 16 + (lane & 15)][(lane >> 4) * 8];
#pragma unroll
        for (int mi = 0; mi < 2; mi++)
#pragma unroll
            for (int ni = 0; ni < 2; ni++)
                acc[mi][ni] = __builtin_amdgcn_mfma_f32_16x16x32_bf16(af[mi], bfr[ni], acc[mi][ni], 0, 0, 0);
        __syncthreads();
    }
#pragma unroll
    for (int mi = 0; mi < 2; mi++)
#pragma unroll
        for (int ni = 0; ni < 2; ni++) {
            int row = m0 + wr * 32 + mi * 16 + (lane >> 4) * 4;
            int col = n0 + wc * 32 + ni * 16 + (lane & 15);
            float bias = bih[col];
#pragma unroll
            for (int i = 0; i < 4; i++)
                xp[(size_t)(row + i) * GA + col] = f2bf(acc[mi][ni][i] + bias);
        }
}

// ---------------- the serial GRU kernel ----------------
struct SA {
    u16 w[144 * 392];
    float red[144 * 4];
    float bhh[144];
    float hrep[4 * 100];
    float hlin[384];
    float xpb[2 * 144];
    int dead;
};
struct SB {
    u16 wy[96 * 392];
    u16 whb[96 * 72];
    float cpl[32 * 96];
    float red[96 * 6];
    float nbuf[96];
    float bhh[96];
    float hrep[6 * 68];
    float hbprev[64];
    int dead;
};
union SMem { SA a; SB b; };

#define CAP (1 << 22)

__global__ __launch_bounds__(576) void k_serial(const float* __restrict__ whhA, const float* __restrict__ bhhA,
                                                const float* __restrict__ wihB, const float* __restrict__ whhB,
                                                const float* __restrict__ bhhB, const u16* __restrict__ xp,
                                                const float* __restrict__ cpart, float* hA, float* hB,
                                                u32* flags, float* __restrict__ yB) {
    __shared__ SMem sm;
    int blk = blockIdx.x;
    int b = blk & 15, role = blk >> 4;
    int tid = threadIdx.x;
    u32* flagA = flags + b * 8;
    u32* flagB = flags + 128 + b * 2;
    if (role < 8) {
        // ================= GRU-A workgroup (48 hidden units) =================
        SA& s = sm.a;
        const int slice = role;
        for (int i = tid; i < 144 * 96; i += 576) {
            int row = i / 96, kq = i % 96;
            int G = (row / 48) * 384 + slice * 48 + (row % 48);
            float4 v = *(const float4*)(whhA + (size_t)G * 384 + kq * 4);
            *(uint2*)&s.w[row * 392 + kq * 4] = pack4(v);
        }
        if (tid < 144) {
            int G = (tid / 48) * 384 + slice * 48 + (tid % 48);
            s.bhh[tid] = bhhA[G];
            s.xpb[tid] = bf2f(xp[(size_t)(b * S_LEN) * GA + G]);
        }
        if (tid < 384) {
            float v = __hip_atomic_load(hA + ((size_t)b * 8 + 7) * UA + tid, __ATOMIC_RELAXED, __HIP_MEMORY_SCOPE_AGENT);
            s.hlin[tid] = v;
            s.hrep[(tid / 96) * 100 + (tid % 96)] = v;
        }
        if (tid == 0) s.dead = 0;
        __syncthreads();
        const int row = tid % 144, kc = tid / 144;
        const uint4* wp = (const uint4*)(s.w + row * 392) + kc * 12;
        const float4* hp = (const float4*)(s.hrep + kc * 100);
        const int G = (tid / 48) * 384 + slice * 48 + (tid % 48);
        for (int t = 0; t < S_LEN; t++) {
            float xpn = 0.f;
            if (tid < 144 && t + 1 < S_LEN) xpn = bf2f(xp[(size_t)(b * S_LEN + t + 1) * GA + G]);
            float s0 = 0, s1 = 0, s2 = 0, s3 = 0;
#pragma unroll
            for (int i = 0; i < 12; i++) {
                uint4 wv = wp[i];
                float4 h0 = hp[2 * i], h1 = hp[2 * i + 1];
                s0 = fmaf(blo(wv.x), h0.x, s0); s1 = fmaf(bhi(wv.x), h0.y, s1);
                s2 = fmaf(blo(wv.y), h0.z, s2); s3 = fmaf(bhi(wv.y), h0.w, s3);
                s0 = fmaf(blo(wv.z), h1.x, s0); s1 = fmaf(bhi(wv.z), h1.y, s1);
                s2 = fmaf(blo(wv.w), h1.z, s2); s3 = fmaf(bhi(wv.w), h1.w, s3);
            }
            s.red[row * 4 + kc] = (s0 + s1) + (s2 + s3);
            __syncthreads();
            if (tid < 48) {
                int u = tid;
                float pr = s.red[u * 4] + s.red[u * 4 + 1] + s.red[u * 4 + 2] + s.red[u * 4 + 3] + s.bhh[u];
                int rz = (48 + u) * 4;
                float pz = s.red[rz] + s.red[rz + 1] + s.red[rz + 2] + s.red[rz + 3] + s.bhh[48 + u];
                int rn = (96 + u) * 4;
                float pn = s.red[rn] + s.red[rn + 1] + s.red[rn + 2] + s.red[rn + 3] + s.bhh[96 + u];
                int cb = (t & 1) * 144;
                float rg = sigm(s.xpb[cb + u] + pr);
                float zg = sigm(s.xpb[cb + 48 + u] + pz);
                float ng = tanh_(s.xpb[cb + 96 + u] + rg * pn);
                float hprev = s.hlin[slice * 48 + u];
                float hnew = (1.f - zg) * ng + zg * hprev;
                __hip_atomic_store(hA + ((size_t)b * 8 + (t & 7)) * UA + slice * 48 + u, hnew,
                                   __ATOMIC_RELAXED, __HIP_MEMORY_SCOPE_AGENT);
            }
            if (tid < 144 && t + 1 < S_LEN) s.xpb[((t + 1) & 1) * 144 + tid] = xpn;
            __syncthreads();
            if (tid == 0) __hip_atomic_store(&flagA[slice], (u32)(t + 1), __ATOMIC_RELEASE, __HIP_MEMORY_SCOPE_AGENT);
            if (!s.dead) {
                if (tid < 8) {
                    int cnt = 0;
                    while ((int)__hip_atomic_load(&flagA[tid], __ATOMIC_ACQUIRE, __HIP_MEMORY_SCOPE_AGENT) < t + 1) {
                        if (++cnt > CAP) { s.dead = 1; break; }
                    }
                } else if (tid < 10 && t >= 7) {
                    int tgt = t - 6, cnt = 0;
                    while ((int)__hip_atomic_load(&flagB[tid - 8], __ATOMIC_ACQUIRE, __HIP_MEMORY_SCOPE_AGENT) < tgt) {
                        if (++cnt > CAP) { s.dead = 1; break; }
                    }
                }
            }
            __syncthreads();
            if (tid < 384) {
                float v = __hip_atomic_load(hA + ((size_t)b * 8 + (t & 7)) * UA + tid,
                                            __ATOMIC_RELAXED, __HIP_MEMORY_SCOPE_AGENT);
                s.hlin[tid] = v;
                s.hrep[(tid / 96) * 100 + (tid % 96)] = v;
            }
            __syncthreads();
        }
    } else {
        // ================= GRU-B workgroup (32 hidden units), pipelined behind A =================
        SB& s = sm.b;
        const int slice = role - 8;
        for (int i = tid; i < 96 * 96; i += 576) {
            int row = i / 96, kq = i % 96;
            int G = (row / 32) * 64 + slice * 32 + (row % 32);
            float4 v = *(const float4*)(wihB + (size_t)G * 512 + kq * 4);
            *(uint2*)&s.wy[row * 392 + kq * 4] = pack4(v);
        }
        for (int i = tid; i < 96 * 16; i += 576) {
            int row = i / 16, kq = i % 16;
            int G = (row / 32) * 64 + slice * 32 + (row % 32);
            float4 v = *(const float4*)(whhB + (size_t)G * 64 + kq * 4);
            *(uint2*)&s.whb[row * 72 + kq * 4] = pack4(v);
        }
        for (int i = tid; i < 32 * 96; i += 576) {
            int fr = i / 96, rw = i % 96;
            int G = (rw / 32) * 64 + slice * 32 + (rw % 32);
            s.cpl[fr * 96 + rw] = cpart[((size_t)b * 32 + fr) * 192 + G];
        }
        if (tid < 96) {
            int G = (tid / 32) * 64 + slice * 32 + (tid % 32);
            s.bhh[tid] = bhhB[G];
        }
        if (tid == 0) s.dead = 0;
        __syncthreads();
        const int row = tid % 96, kc = tid / 96;
        const uint4* wp = (const uint4*)(s.wy + row * 392) + kc * 8;
        const float4* hp = (const float4*)(s.hrep + kc * 68);
        for (int t = 0; t < S_LEN; t++) {
            if (!s.dead) {
                if (tid < 8) {
                    int cnt = 0;
                    while ((int)__hip_atomic_load(&flagA[tid], __ATOMIC_ACQUIRE, __HIP_MEMORY_SCOPE_AGENT) < t + 1) {
                        if (++cnt > CAP) { s.dead = 1; break; }
                    }
                } else if (tid == 8) {
                    int cnt = 0;
                    while ((int)__hip_atomic_load(&flagB[1 - slice], __ATOMIC_ACQUIRE, __HIP_MEMORY_SCOPE_AGENT) < t) {
                        if (++cnt > CAP) { s.dead = 1; break; }
                    }
                }
            }
            __syncthreads();
            if (tid < 384) {
                float v = __hip_atomic_load(hA + ((size_t)b * 8 + (t & 7)) * UA + tid,
                                            __ATOMIC_RELAXED, __HIP_MEMORY_SCOPE_AGENT);
                s.hrep[(tid / 64) * 68 + (tid & 63)] = v;
            } else if (tid < 448) {
                int u = tid - 384;
                s.hbprev[u] = __hip_atomic_load(hB + ((size_t)b * 2 + ((t + 1) & 1)) * UB + u,
                                                __ATOMIC_RELAXED, __HIP_MEMORY_SCOPE_AGENT);
            }
            __syncthreads();
            float s0 = 0, s1 = 0, s2 = 0, s3 = 0;
#pragma unroll
            for (int i = 0; i < 8; i++) {
                uint4 wv = wp[i];
                float4 h0 = hp[2 * i], h1 = hp[2 * i + 1];
                s0 = fmaf(blo(wv.x), h0.x, s0); s1 = fmaf(bhi(wv.x), h0.y, s1);
                s2 = fmaf(blo(wv.y), h0.z, s2); s3 = fmaf(bhi(wv.y), h0.w, s3);
                s0 = fmaf(blo(wv.z), h1.x, s0); s1 = fmaf(bhi(wv.z), h1.y, s1);
                s2 = fmaf(blo(wv.w), h1.z, s2); s3 = fmaf(bhi(wv.w), h1.w, s3);
            }
            s.red[row * 6 + kc] = (s0 + s1) + (s2 + s3);
            if (tid < 96) {
                const uint4* w2 = (const uint4*)(s.whb + tid * 72);
                const float4* h2 = (const float4*)s.hbprev;
                float n0 = 0, n1 = 0, n2 = 0, n3 = 0;
#pragma unroll
                for (int i = 0; i < 8; i++) {
                    uint4 wv = w2[i];
                    float4 h0 = h2[2 * i], h1 = h2[2 * i + 1];
                    n0 = fmaf(blo(wv.x), h0.x, n0); n1 = fmaf(bhi(wv.x), h0.y, n1);
                    n2 = fmaf(blo(wv.y), h0.z, n2); n3 = fmaf(bhi(wv.y), h0.w, n3);
                    n0 = fmaf(blo(wv.z), h1.x, n0); n1 = fmaf(bhi(wv.z), h1.y, n1);
                    n2 = fmaf(blo(wv.w), h1.z, n2); n3 = fmaf(bhi(wv.w), h1.w, n3);
                }
                s.nbuf[tid] = (n0 + n1) + (n2 + n3) + s.bhh[tid];
            }
            __syncthreads();
            if (tid < 32) {
                int u = tid, ug = slice * 32 + u, fr = t / 160;
                float px0 = 0, px1 = 0, px2 = 0;
#pragma unroll
                for (int j = 0; j < 6; j++) {
                    px0 += s.red[u * 6 + j];
                    px1 += s.red[(32 + u) * 6 + j];
                    px2 += s.red[(64 + u) * 6 + j];
                }
                px0 += s.cpl[fr * 96 + u];
                px1 += s.cpl[fr * 96 + 32 + u];
                px2 += s.cpl[fr * 96 + 64 + u];
                float rg = sigm(px0 + s.nbuf[u]);
                float zg = sigm(px1 + s.nbuf[32 + u]);
                float ng = tanh_(px2 + rg * s.nbuf[64 + u]);
                float hprev = s.hbprev[ug];
                float hnew = (1.f - zg) * ng + zg * hprev;
                __hip_atomic_store(hB + ((size_t)b * 2 + (t & 1)) * UB + ug, hnew,
                                   __ATOMIC_RELAXED, __HIP_MEMORY_SCOPE_AGENT);
                yB[((size_t)b * S_LEN + t) * UB + ug] = hnew;
            }
            __syncthreads();
            if (tid == 0) __hip_atomic_store(&flagB[slice], (u32)(t + 1), __ATOMIC_RELEASE, __HIP_MEMORY_SCOPE_AGENT);
        }
    }
}

// ---------------- dual FC + log_softmax ----------------
__global__ __launch_bounds__(256) void k_fc(const float* __restrict__ yB, const float* __restrict__ w1,
                                            const float* __restrict__ b1, const float* __restrict__ w2,
                                            const float* __restrict__ b2, const float* __restrict__ alpha,
                                            const float* __restrict__ beta, float* __restrict__ out) {
    __shared__ float yb[4][64];
    __shared__ float vb[4][256];
    int tid = threadIdx.x;
    size_t r0 = (size_t)blockIdx.x * 4;
    { int r = tid >> 6, k = tid & 63; yb[r][k] = yB[(r0 + r) * 64 + k]; }
    __syncthreads();
    int o = tid;
    float a1[4] = {0, 0, 0, 0}, a2[4] = {0, 0, 0, 0};
    for (int k = 0; k < 64; k += 4) {
        float4 u = *(const float4*)(w1 + o * 64 + k);
        float4 v = *(const float4*)(w2 + o * 64 + k);
#pragma unroll
        for (int r = 0; r < 4; r++) {
            float y0 = yb[r][k], y1 = yb[r][k + 1], y2 = yb[r][k + 2], y3 = yb[r][k + 3];
            a1[r] = fmaf(u.x, y0, fmaf(u.y, y1, fmaf(u.z, y2, fmaf(u.w, y3, a1[r]))));
            a2[r] = fmaf(v.x, y0, fmaf(v.y, y1, fmaf(v.z, y2, fmaf(v.w, y3, a2[r]))));
        }
    }
    float al = alpha[o], be = beta[o], c1 = b1[o], c2 = b2[o];
#pragma unroll
    for (int r = 0; r < 4; r++)
        vb[r][o] = al * tanh_(a1[r] + c1) + be * tanh_(a2[r] + c2);
    __syncthreads();
    int wv = tid >> 6, l = tid & 63;
    float x0 = vb[wv][l], x1 = vb[wv][64 + l], x2 = vb[wv][128 + l], x3 = vb[wv][192 + l];
    float m = fmaxf(fmaxf(x0, x1), fmaxf(x2, x3));
#pragma unroll
    for (int off = 1; off < 64; off <<= 1) m = fmaxf(m, __shfl_xor(m, off));
    float sum = __expf(x0 - m) + __expf(x1 - m) + __expf(x2 - m) + __expf(x3 - m);
#pragma unroll
    for (int off = 1; off < 64; off <<= 1) sum += __shfl_xor(sum, off);
    float lse = m + __logf(sum);
    float* po = out + (r0 + wv) * 256;
    po[l] = x0 - lse;
    po[64 + l] = x1 - lse;
    po[128 + l] = x2 - lse;
    po[192 + l] = x3 - lse;
}

extern "C" void kernel_launch(void* const* d_in, const int* in_sizes, int n_in,
                              void* d_out, int out_size, void* d_ws, size_t ws_size,
                              hipStream_t stream) {
    const float* features = (const float*)d_in[0];
    const int* periods = (const int*)d_in[1];
    const int* signals = (const int*)d_in[2];
    const float* gruA0 = (const float*)d_in[3];
    const float* gruB0 = (const float*)d_in[4];
    const float* period_emb = (const float*)d_in[5];
    const float* signal_emb = (const float*)d_in[6];
    const float* conv1_w = (const float*)d_in[7];
    const float* conv1_b = (const float*)d_in[8];
    const float* conv2_w = (const float*)d_in[9];
    const float* conv2_b = (const float*)d_in[10];
    const float* fd1_w = (const float*)d_in[11];
    const float* fd1_b = (const float*)d_in[12];
    const float* fd2_w = (const float*)d_in[13];
    const float* fd2_b = (const float*)d_in[14];
    const float* grua_wih = (const float*)d_in[15];
    const float* grua_whh = (const float*)d_in[16];
    const float* grua_bih = (const float*)d_in[17];
    const float* grua_bhh = (const float*)d_in[18];
    const float* grub_wih = (const float*)d_in[19];
    const float* grub_whh = (const float*)d_in[20];
    const float* grub_bih = (const float*)d_in[21];
    const float* grub_bhh = (const float*)d_in[22];
    const float* fc1_w = (const float*)d_in[23];
    const float* fc1_b = (const float*)d_in[24];
    const float* fc2_w = (const float*)d_in[25];
    const float* fc2_b = (const float*)d_in[26];
    const float* alpha = (const float*)d_in[27];
    const float* beta = (const float*)d_in[28];
    float* out = (float*)d_out;

    char* ws = (char*)d_ws;
    size_t off = 0;
    auto alloc = [&](size_t bytes) { void* p = ws + off; off += (bytes + 255) & ~(size_t)255; return p; };
    u16* xp = (u16*)alloc((size_t)16 * 5120 * 1152 * 2);
    u16* wihA = (u16*)alloc((size_t)1152 * 512 * 2);
    float* c1 = (float*)alloc((size_t)16 * 34 * 128 * 4);
    float* c2 = (float*)alloc((size_t)16 * 32 * 128 * 4);
    float* cc = (float*)alloc((size_t)16 * 32 * 128 * 4);
    float* cpart = (float*)alloc((size_t)16 * 32 * 192 * 4);
    float* yB = (float*)alloc((size_t)16 * 5120 * 64 * 4);
    float* hA = (float*)alloc((size_t)16 * 8 * 384 * 4);
    float* hB = (float*)alloc((size_t)16 * 2 * 64 * 4);
    u32* flags = (u32*)alloc(1024);

    k_cvt<<<dim3(2304), dim3(256), 0, stream>>>(grua_wih, wihA);
    k_frame1<<<dim3(34, 16), dim3(128), 0, stream>>>(features, periods, period_emb, conv1_w, conv1_b, c1);
    k_frame2<<<dim3(32, 16), dim3(128), 0, stream>>>(c1, conv2_w, conv2_b, c2);
    k_fd<<<dim3(32, 16), dim3(128), 0, stream>>>(c2, fd1_w, fd1_b, fd2_w, fd2_b, cc);
    k_cpart<<<dim3(32, 16), dim3(192), 0, stream>>>(cc, grub_wih, grub_bih, cpart);
    k_init<<<dim3(8), dim3(1024), 0, stream>>>(gruA0, gruB0, hA, hB, flags);
    k_gemm<<<dim3(1280, 18), dim3(256), 0, stream>>>(signals, signal_emb, cc, wihA, grua_bih, xp);
    k_serial<<<dim3(160), dim3(576), 0, stream>>>(grua_whh, grua_bhh, grub_wih, grub_whh, grub_bhh,
                                                  xp, cpart, hA, hB, flags, yB);
    k_fc<<<dim3(20480), dim3(256), 0, stream>>>(yB, fc1_w, fc1_b, fc2_w, fc2_b, alpha, beta, out);
}

// Round 2
// 20352.060 us; speedup vs baseline: 1.4045x; 1.4045x over previous
//
#include <hip/hip_runtime.h>

typedef unsigned short u16;
typedef unsigned int u32;
typedef __attribute__((ext_vector_type(8))) short bf16x8;
typedef __attribute__((ext_vector_type(4))) float f32x4;

#define S_LEN 5120
#define NB 16
#define UA 384
#define UB 64
#define GA 1152
#define CAP (1 << 22)

__device__ __forceinline__ float bf2f(u16 u) { return __uint_as_float(((u32)u) << 16); }
__device__ __forceinline__ u16 f2bf(float f) {
    u32 x = __float_as_uint(f);
    return (u16)((x + 0x7fffu + ((x >> 16) & 1u)) >> 16);
}
__device__ __forceinline__ float blo(u32 w) { return __uint_as_float(w << 16); }
__device__ __forceinline__ float bhi(u32 w) { return __uint_as_float(w & 0xffff0000u); }
__device__ __forceinline__ float sigm(float x) { return 1.f / (1.f + __expf(-x)); }
__device__ __forceinline__ float tanh_(float x) { float e = __expf(2.f * x); return 1.f - 2.f / (e + 1.f); }
__device__ __forceinline__ uint2 pack4(float4 v) {
    return make_uint2((u32)f2bf(v.x) | ((u32)f2bf(v.y) << 16),
                      (u32)f2bf(v.z) | ((u32)f2bf(v.w) << 16));
}

// ---------------- convert grua_wih to bf16 ----------------
__global__ __launch_bounds__(256) void k_cvt(const float* __restrict__ src, u16* __restrict__ dst) {
    int i = blockIdx.x * 256 + threadIdx.x;
    dst[i] = f2bf(src[i]);
}

// ---------------- frame-rate network ----------------
__global__ __launch_bounds__(128) void k_frame1(const float* __restrict__ features, const int* __restrict__ periods,
                                                const float* __restrict__ pemb, const float* __restrict__ w,
                                                const float* __restrict__ bias, float* __restrict__ c1) {
    __shared__ float fin[3][84];
    int t = blockIdx.x, b = blockIdx.y, o = threadIdx.x;
    for (int i = threadIdx.x; i < 252; i += 128) {
        int kk = i / 84, ci = i % 84, tt = t + kk;
        float v;
        if (ci < 20) v = features[(b * 36 + tt) * 20 + ci];
        else v = pemb[periods[b * 36 + tt] * 64 + (ci - 20)];
        fin[kk][ci] = v;
    }
    __syncthreads();
    float acc = bias[o];
    for (int kk = 0; kk < 3; kk++)
        for (int ci = 0; ci < 84; ci++)
            acc = fmaf(fin[kk][ci], w[o * 252 + ci * 3 + kk], acc);
    c1[(b * 34 + t) * 128 + o] = tanh_(acc);
}

__global__ __launch_bounds__(128) void k_frame2(const float* __restrict__ c1, const float* __restrict__ w,
                                                const float* __restrict__ bias, float* __restrict__ c2) {
    __shared__ float fin[3][128];
    int t = blockIdx.x, b = blockIdx.y, o = threadIdx.x;
    for (int i = threadIdx.x; i < 384; i += 128) {
        int kk = i >> 7, ci = i & 127;
        fin[kk][ci] = c1[(b * 34 + t + kk) * 128 + ci];
    }
    __syncthreads();
    float acc = bias[o];
    for (int kk = 0; kk < 3; kk++)
        for (int ci = 0; ci < 128; ci++)
            acc = fmaf(fin[kk][ci], w[o * 384 + ci * 3 + kk], acc);
    c2[(b * 32 + t) * 128 + o] = tanh_(acc);
}

__global__ __launch_bounds__(128) void k_fd(const float* __restrict__ c2, const float* __restrict__ w1,
                                            const float* __restrict__ b1, const float* __restrict__ w2,
                                            const float* __restrict__ b2, float* __restrict__ cc) {
    __shared__ float a0[128], a1s[128];
    int t = blockIdx.x, b = blockIdx.y, o = threadIdx.x;
    a0[o] = c2[(b * 32 + t) * 128 + o];
    __syncthreads();
    float acc = b1[o];
    for (int k = 0; k < 128; k++) acc = fmaf(a0[k], w1[o * 128 + k], acc);
    a1s[o] = tanh_(acc);
    __syncthreads();
    float acc2 = b2[o];
    for (int k = 0; k < 128; k++) acc2 = fmaf(a1s[k], w2[o * 128 + k], acc2);
    cc[(b * 32 + t) * 128 + o] = tanh_(acc2);
}

// cpart[b][fr][192] = grub_wih[:,384:512] @ c[b][fr] + grub_bih
__global__ __launch_bounds__(192) void k_cpart(const float* __restrict__ cc, const float* __restrict__ wihB,
                                               const float* __restrict__ bihB, float* __restrict__ cpart) {
    __shared__ float cl[128];
    int fr = blockIdx.x, b = blockIdx.y, o = threadIdx.x;
    if (o < 128) cl[o] = cc[(b * 32 + fr) * 128 + o];
    __syncthreads();
    float acc = bihB[o];
    for (int k = 0; k < 128; k++) acc = fmaf(cl[k], wihB[o * 512 + 384 + k], acc);
    cpart[((size_t)b * 32 + fr) * 192 + o] = acc;
}

// ---------------- init flags ----------------
__global__ __launch_bounds__(128) void k_init(u32* flags) {
    flags[threadIdx.x] = 0;
}

// ---------------- GRU-A input projection GEMM ----------------
__global__ __launch_bounds__(256) void k_gemm(const int* __restrict__ signals, const float* __restrict__ semb,
                                              const float* __restrict__ c, const u16* __restrict__ wih,
                                              const float* __restrict__ bih, u16* __restrict__ xp) {
    __shared__ u16 As[64][40];
    __shared__ u16 Bs[64][40];
    int m0 = blockIdx.x * 64, n0 = blockIdx.y * 64;
    int tid = threadIdx.x;
    int r = tid >> 2, kc = tid & 3;
    int lane = tid & 63, wv = tid >> 6;
    int wr = wv >> 1, wc = wv & 1;
    int mrow = m0 + r;
    int b = mrow / S_LEN, s = mrow % S_LEN;
    const int* sigrow = signals + mrow * 3;
    const float* crow = c + ((size_t)(b * 32) + s / 160) * 128;
    f32x4 acc[2][2];
#pragma unroll
    for (int i = 0; i < 2; i++)
#pragma unroll
        for (int j = 0; j < 2; j++) { acc[i][j][0] = 0.f; acc[i][j][1] = 0.f; acc[i][j][2] = 0.f; acc[i][j][3] = 0.f; }
    for (int k0 = 0; k0 < 512; k0 += 32) {
        int k = k0 + kc * 8;
        float v[8];
        if (k < 384) {
            int idx = sigrow[k >> 7];
            const float* src = semb + idx * 128 + (k & 127);
#pragma unroll
            for (int j = 0; j < 8; j++) v[j] = src[j];
        } else {
            const float* src = crow + (k - 384);
#pragma unroll
            for (int j = 0; j < 8; j++) v[j] = src[j];
        }
        u32 pk[4];
#pragma unroll
        for (int j = 0; j < 4; j++) pk[j] = (u32)f2bf(v[2 * j]) | ((u32)f2bf(v[2 * j + 1]) << 16);
        *(uint4*)&As[r][kc * 8] = *(uint4*)pk;
        *(uint4*)&Bs[r][kc * 8] = *(const uint4*)&wih[(size_t)(n0 + r) * 512 + k];
        __syncthreads();
        bf16x8 af[2], bfr[2];
#pragma unroll
        for (int mi = 0; mi < 2; mi++) af[mi] = *(const bf16x8*)&As[wr * 32 + mi * 16 + (lane & 15)][(lane >> 4) * 8];
#pragma unroll
        for (int ni = 0; ni < 2; ni++) bfr[ni] = *(const bf16x8*)&Bs[wc * 32 + ni * 16 + (lane & 15)][(lane >> 4) * 8];
#pragma unroll
        for (int mi = 0; mi < 2; mi++)
#pragma unroll
            for (int ni = 0; ni < 2; ni++)
                acc[mi][ni] = __builtin_amdgcn_mfma_f32_16x16x32_bf16(af[mi], bfr[ni], acc[mi][ni], 0, 0, 0);
        __syncthreads();
    }
#pragma unroll
    for (int mi = 0; mi < 2; mi++)
#pragma unroll
        for (int ni = 0; ni < 2; ni++) {
            int row = m0 + wr * 32 + mi * 16 + (lane >> 4) * 4;
            int col = n0 + wc * 32 + ni * 16 + (lane & 15);
            float bias = bih[col];
#pragma unroll
            for (int i = 0; i < 4; i++)
                xp[(size_t)(row + i) * GA + col] = f2bf(acc[mi][ni][i] + bias);
        }
}

// ---------------- the serial GRU kernel: 8 WGs per batch, A + B-slice fused ----------------
struct __align__(16) SMemS {
    u16 wA[144 * 392];    // GRU-A whh slice (rows gate*48+u, K=384), 49 uint4/row
    u16 wBy[24 * 392];    // GRU-B wih[:,0:384] slice (rows gate*8+u)
    u16 wBh[24 * 72];     // GRU-B whh slice (K=64), 9 uint4/row
    float cpl[32 * 26];   // cpart slice per frame (24 rows, pad 26)
    float bhhA[144];
    float bhhB[24];
    float hrep[4 * 104];  // hA(t-1): chunk c holds hA[c*96 .. c*96+95]
    float hxB[72];        // hB(t-2), 64 + pad
    float xpb[2 * 144];   // xp double buffer for owned A gate rows
    float redA[4 * 148];  // [kc][row]
    float redBy[8 * 26];  // [kc][row]
    float redBh[2 * 26];
    int dead;
};

__global__ __launch_bounds__(576) void k_serial(const float* __restrict__ whhA, const float* __restrict__ bhhA,
                                                const float* __restrict__ wihB, const float* __restrict__ whhB,
                                                const float* __restrict__ bhhB, const u16* __restrict__ xp,
                                                const float* __restrict__ cpart, const float* __restrict__ h0a,
                                                const float* __restrict__ h0b, float* hEx, u32* flags,
                                                float* __restrict__ yB) {
    __shared__ SMemS s;
    const int blk = blockIdx.x;
    const int b = blk & 15, slice = blk >> 4;   // 16 batches x 8 slices
    const int tid = threadIdx.x;
    u32* flagp = flags + b * 8;

    // ---- load weights ----
    for (int i = tid; i < 144 * 96; i += 576) {
        int row = i / 96, kq = i % 96;
        int G = (row / 48) * 384 + slice * 48 + (row % 48);
        float4 v = *(const float4*)(whhA + (size_t)G * 384 + kq * 4);
        *(uint2*)&s.wA[row * 392 + kq * 4] = pack4(v);
    }
    for (int i = tid; i < 24 * 96; i += 576) {
        int row = i / 96, kq = i % 96;
        int Gb = (row / 8) * 64 + slice * 8 + (row % 8);
        float4 v = *(const float4*)(wihB + (size_t)Gb * 512 + kq * 4);
        *(uint2*)&s.wBy[row * 392 + kq * 4] = pack4(v);
    }
    for (int i = tid; i < 24 * 16; i += 576) {
        int row = i / 16, kq = i % 16;
        int Gb = (row / 8) * 64 + slice * 8 + (row % 8);
        float4 v = *(const float4*)(whhB + (size_t)Gb * 64 + kq * 4);
        *(uint2*)&s.wBh[row * 72 + kq * 4] = pack4(v);
    }
    for (int i = tid; i < 32 * 24; i += 576) {
        int fr = i / 24, rw = i % 24;
        int Gb = (rw / 8) * 64 + slice * 8 + (rw % 8);
        s.cpl[fr * 26 + rw] = cpart[((size_t)b * 32 + fr) * 192 + Gb];
    }
    if (tid < 144) {
        int G = (tid / 48) * 384 + slice * 48 + (tid % 48);
        s.bhhA[tid] = bhhA[G];
    } else if (tid < 168) {
        int j = tid - 144;
        int Gb = (j / 8) * 64 + slice * 8 + (j % 8);
        s.bhhB[j] = bhhB[Gb];
    }
    // ---- initial state ----
    if (tid < 384) {
        float v = h0a[b * 384 + tid];
        s.hrep[(tid / 96) * 104 + (tid % 96)] = v;
    } else if (tid < 448) {
        s.hxB[tid - 384] = h0b[b * 64 + (tid - 384)];
    }
    // per-thread constants
    const int arow = tid >> 2, akc = tid & 3;
    const uint4* wpA = (const uint4*)s.wA + arow * 49 + akc * 12;
    const float4* hpA = (const float4*)(s.hrep + akc * 104);
    const int brow2 = tid >> 3, bkc = tid & 7;
    const uint4* wpBy = (const uint4*)s.wBy + brow2 * 49 + bkc * 6;
    const float4* hpBy = (const float4*)(s.hrep + (bkc >> 1) * 104 + (bkc & 1) * 48);
    const int jB = tid - 192, brow3 = jB >> 1, bk = jB & 1;
    const uint4* wpBh = (const uint4*)s.wBh + brow3 * 9 + bk * 4;
    const float4* hpBh = (const float4*)(s.hxB + bk * 32);
    const int prow = tid - 64;
    const int Gp = (tid >= 64 && tid < 208) ? (prow / 48) * 384 + slice * 48 + (prow % 48) : 0;
    // xp(0) preload
    if (tid >= 64 && tid < 208)
        s.xpb[prow] = bf2f(xp[((size_t)b * S_LEN) * GA + Gp]);
    if (tid == 0) s.dead = 0;
    __syncthreads();

    for (int t = 0; t <= S_LEN; ++t) {
        const bool hasA = (t < S_LEN);
        const bool hasB = (t > 0);
        // issue xp(t+1) prefetch early
        u16 xpr = 0;
        const bool pref = hasA && tid >= 64 && tid < 208 && (t + 1 < S_LEN);
        if (pref) xpr = xp[((size_t)b * S_LEN + t + 1) * GA + Gp];
        // A matvec: whhA_slice @ hA(t-1)
        if (hasA) {
            float s0 = 0, s1 = 0, s2 = 0, s3 = 0;
#pragma unroll
            for (int i = 0; i < 12; i++) {
                uint4 wv = wpA[i];
                float4 h0 = hpA[2 * i], h1 = hpA[2 * i + 1];
                s0 = fmaf(blo(wv.x), h0.x, s0); s1 = fmaf(bhi(wv.x), h0.y, s1);
                s2 = fmaf(blo(wv.y), h0.z, s2); s3 = fmaf(bhi(wv.y), h0.w, s3);
                s0 = fmaf(blo(wv.z), h1.x, s0); s1 = fmaf(bhi(wv.z), h1.y, s1);
                s2 = fmaf(blo(wv.w), h1.z, s2); s3 = fmaf(bhi(wv.w), h1.w, s3);
            }
            s.redA[akc * 148 + arow] = (s0 + s1) + (s2 + s3);
        }
        // B matvecs: wBy @ hA(t-1), wBh @ hB(t-2)   (computes hB(t-1))
        if (hasB) {
            if (tid < 192) {
                float s0 = 0, s1 = 0, s2 = 0, s3 = 0;
#pragma unroll
                for (int i = 0; i < 6; i++) {
                    uint4 wv = wpBy[i];
                    float4 h0 = hpBy[2 * i], h1 = hpBy[2 * i + 1];
                    s0 = fmaf(blo(wv.x), h0.x, s0); s1 = fmaf(bhi(wv.x), h0.y, s1);
                    s2 = fmaf(blo(wv.y), h0.z, s2); s3 = fmaf(bhi(wv.y), h0.w, s3);
                    s0 = fmaf(blo(wv.z), h1.x, s0); s1 = fmaf(bhi(wv.z), h1.y, s1);
                    s2 = fmaf(blo(wv.w), h1.z, s2); s3 = fmaf(bhi(wv.w), h1.w, s3);
                }
                s.redBy[bkc * 26 + brow2] = (s0 + s1) + (s2 + s3);
            } else if (tid < 240) {
                float s0 = 0, s1 = 0, s2 = 0, s3 = 0;
#pragma unroll
                for (int i = 0; i < 4; i++) {
                    uint4 wv = wpBh[i];
                    float4 h0 = hpBh[2 * i], h1 = hpBh[2 * i + 1];
                    s0 = fmaf(blo(wv.x), h0.x, s0); s1 = fmaf(bhi(wv.x), h0.y, s1);
                    s2 = fmaf(blo(wv.y), h0.z, s2); s3 = fmaf(bhi(wv.y), h0.w, s3);
                    s0 = fmaf(blo(wv.z), h1.x, s0); s1 = fmaf(bhi(wv.z), h1.y, s1);
                    s2 = fmaf(blo(wv.w), h1.z, s2); s3 = fmaf(bhi(wv.w), h1.w, s3);
                }
                s.redBh[bk * 26 + brow3] = (s0 + s1) + (s2 + s3);
            }
        }
        __syncthreads();  // B1: red* complete, previous hrep/hxB consumed

        float* rec = hEx + (((size_t)b * 2 + (t & 1)) * 8 + slice) * 64;
        // ---- wave 0: gates + store + flag + poll ----
        if (tid < 48) {
            if (hasA) {
                int u = tid;
                float pr = s.redA[u] + s.redA[148 + u] + s.redA[296 + u] + s.redA[444 + u] + s.bhhA[u];
                float pz = s.redA[48 + u] + s.redA[148 + 48 + u] + s.redA[296 + 48 + u] + s.redA[444 + 48 + u] + s.bhhA[48 + u];
                float pn = s.redA[96 + u] + s.redA[148 + 96 + u] + s.redA[296 + 96 + u] + s.redA[444 + 96 + u] + s.bhhA[96 + u];
                const float* xb = s.xpb + (t & 1) * 144;
                float rg = sigm(xb[u] + pr);
                float zg = sigm(xb[48 + u] + pz);
                float ng = tanh_(xb[96 + u] + rg * pn);
                int g0 = slice * 48 + u;
                float hprev = s.hrep[(g0 / 96) * 104 + (g0 % 96)];
                float hnew = (1.f - zg) * ng + zg * hprev;
                __hip_atomic_store(rec + u, hnew, __ATOMIC_RELAXED, __HIP_MEMORY_SCOPE_AGENT);
            }
        } else if (tid < 56) {
            int u = tid - 48;
            float hbnew;
            if (hasB) {
                float xr = 0, xz = 0, xn = 0;
#pragma unroll
                for (int j = 0; j < 8; j++) {
                    xr += s.redBy[j * 26 + u];
                    xz += s.redBy[j * 26 + 8 + u];
                    xn += s.redBy[j * 26 + 16 + u];
                }
                int fr = (t - 1) / 160;
                const float* cp = s.cpl + fr * 26;
                xr += cp[u]; xz += cp[8 + u]; xn += cp[16 + u];
                float hr = s.redBh[u] + s.redBh[26 + u] + s.bhhB[u];
                float hz = s.redBh[8 + u] + s.redBh[26 + 8 + u] + s.bhhB[8 + u];
                float hn = s.redBh[16 + u] + s.redBh[26 + 16 + u] + s.bhhB[16 + u];
                float rg = sigm(xr + hr);
                float zg = sigm(xz + hz);
                float ng = tanh_(xn + rg * hn);
                float hprev = s.hxB[slice * 8 + u];
                hbnew = (1.f - zg) * ng + zg * hprev;
                yB[((size_t)b * S_LEN + (t - 1)) * UB + slice * 8 + u] = hbnew;
            } else {
                hbnew = s.hxB[slice * 8 + u];
            }
            if (hasA) __hip_atomic_store(rec + 48 + u, hbnew, __ATOMIC_RELAXED, __HIP_MEMORY_SCOPE_AGENT);
        }
        if (hasA) {
            if (tid < 64) {
                asm volatile("s_waitcnt vmcnt(0)" ::: "memory");  // drain h stores (wave 0 only)
                if (tid == 0)
                    __hip_atomic_store(&flagp[slice], (u32)(t + 1), __ATOMIC_RELAXED, __HIP_MEMORY_SCOPE_AGENT);
                if (tid < 8 && !s.dead) {
                    int cnt = 0;
                    while ((int)__hip_atomic_load(&flagp[tid], __ATOMIC_RELAXED, __HIP_MEMORY_SCOPE_AGENT) < t + 1) {
                        if (++cnt > CAP) { s.dead = 1; break; }
                    }
                }
                asm volatile("" ::: "memory");
            }
            // other waves: commit xp(t+1) to LDS while wave 0 syncs
            if (pref) s.xpb[((t + 1) & 1) * 144 + prow] = bf2f(xpr);
            __syncthreads();  // B2: all flags seen; safe to reload
            if (tid < 512) {
                int role = tid >> 6, ii = tid & 63;
                if (ii < 56) {
                    float v = __hip_atomic_load(hEx + (((size_t)b * 2 + (t & 1)) * 8 + role) * 64 + ii,
                                                __ATOMIC_RELAXED, __HIP_MEMORY_SCOPE_AGENT);
                    if (ii < 48) {
                        int g = role * 48 + ii;
                        s.hrep[(g / 96) * 104 + (g % 96)] = v;
                    } else {
                        s.hxB[role * 8 + (ii - 48)] = v;
                    }
                }
            }
            __syncthreads();  // B3: hrep/hxB ready for next step
        }
    }
}

// ---------------- dual FC + log_softmax ----------------
__global__ __launch_bounds__(256) void k_fc(const float* __restrict__ yB, const float* __restrict__ w1,
                                            const float* __restrict__ b1, const float* __restrict__ w2,
                                            const float* __restrict__ b2, const float* __restrict__ alpha,
                                            const float* __restrict__ beta, float* __restrict__ out) {
    __shared__ float yb[4][64];
    __shared__ float vb[4][256];
    int tid = threadIdx.x;
    size_t r0 = (size_t)blockIdx.x * 4;
    { int r = tid >> 6, k = tid & 63; yb[r][k] = yB[(r0 + r) * 64 + k]; }
    __syncthreads();
    int o = tid;
    float a1[4] = {0, 0, 0, 0}, a2[4] = {0, 0, 0, 0};
    for (int k = 0; k < 64; k += 4) {
        float4 u = *(const float4*)(w1 + o * 64 + k);
        float4 v = *(const float4*)(w2 + o * 64 + k);
#pragma unroll
        for (int r = 0; r < 4; r++) {
            float y0 = yb[r][k], y1 = yb[r][k + 1], y2 = yb[r][k + 2], y3 = yb[r][k + 3];
            a1[r] = fmaf(u.x, y0, fmaf(u.y, y1, fmaf(u.z, y2, fmaf(u.w, y3, a1[r]))));
            a2[r] = fmaf(v.x, y0, fmaf(v.y, y1, fmaf(v.z, y2, fmaf(v.w, y3, a2[r]))));
        }
    }
    float al = alpha[o], be = beta[o], c1 = b1[o], c2 = b2[o];
#pragma unroll
    for (int r = 0; r < 4; r++)
        vb[r][o] = al * tanh_(a1[r] + c1) + be * tanh_(a2[r] + c2);
    __syncthreads();
    int wv = tid >> 6, l = tid & 63;
    float x0 = vb[wv][l], x1 = vb[wv][64 + l], x2 = vb[wv][128 + l], x3 = vb[wv][192 + l];
    float m = fmaxf(fmaxf(x0, x1), fmaxf(x2, x3));
#pragma unroll
    for (int off = 1; off < 64; off <<= 1) m = fmaxf(m, __shfl_xor(m, off));
    float sum = __expf(x0 - m) + __expf(x1 - m) + __expf(x2 - m) + __expf(x3 - m);
#pragma unroll
    for (int off = 1; off < 64; off <<= 1) sum += __shfl_xor(sum, off);
    float lse = m + __logf(sum);
    float* po = out + (r0 + wv) * 256;
    po[l] = x0 - lse;
    po[64 + l] = x1 - lse;
    po[128 + l] = x2 - lse;
    po[192 + l] = x3 - lse;
}

extern "C" void kernel_launch(void* const* d_in, const int* in_sizes, int n_in,
                              void* d_out, int out_size, void* d_ws, size_t ws_size,
                              hipStream_t stream) {
    const float* features = (const float*)d_in[0];
    const int* periods = (const int*)d_in[1];
    const int* signals = (const int*)d_in[2];
    const float* gruA0 = (const float*)d_in[3];
    const float* gruB0 = (const float*)d_in[4];
    const float* period_emb = (const float*)d_in[5];
    const float* signal_emb = (const float*)d_in[6];
    const float* conv1_w = (const float*)d_in[7];
    const float* conv1_b = (const float*)d_in[8];
    const float* conv2_w = (const float*)d_in[9];
    const float* conv2_b = (const float*)d_in[10];
    const float* fd1_w = (const float*)d_in[11];
    const float* fd1_b = (const float*)d_in[12];
    const float* fd2_w = (const float*)d_in[13];
    const float* fd2_b = (const float*)d_in[14];
    const float* grua_wih = (const float*)d_in[15];
    const float* grua_whh = (const float*)d_in[16];
    const float* grua_bih = (const float*)d_in[17];
    const float* grua_bhh = (const float*)d_in[18];
    const float* grub_wih = (const float*)d_in[19];
    const float* grub_whh = (const float*)d_in[20];
    const float* grub_bih = (const float*)d_in[21];
    const float* grub_bhh = (const float*)d_in[22];
    const float* fc1_w = (const float*)d_in[23];
    const float* fc1_b = (const float*)d_in[24];
    const float* fc2_w = (const float*)d_in[25];
    const float* fc2_b = (const float*)d_in[26];
    const float* alpha = (const float*)d_in[27];
    const float* beta = (const float*)d_in[28];
    float* out = (float*)d_out;

    char* ws = (char*)d_ws;
    size_t off = 0;
    auto alloc = [&](size_t bytes) { void* p = ws + off; off += (bytes + 255) & ~(size_t)255; return p; };
    u16* xp = (u16*)alloc((size_t)16 * 5120 * 1152 * 2);
    u16* wihA = (u16*)alloc((size_t)1152 * 512 * 2);
    float* c1 = (float*)alloc((size_t)16 * 34 * 128 * 4);
    float* c2 = (float*)alloc((size_t)16 * 32 * 128 * 4);
    float* cc = (float*)alloc((size_t)16 * 32 * 128 * 4);
    float* cpart = (float*)alloc((size_t)16 * 32 * 192 * 4);
    float* yB = (float*)alloc((size_t)16 * 5120 * 64 * 4);
    float* hEx = (float*)alloc((size_t)16 * 2 * 8 * 64 * 4);
    u32* flags = (u32*)alloc(1024);

    k_cvt<<<dim3(2304), dim3(256), 0, stream>>>(grua_wih, wihA);
    k_frame1<<<dim3(34, 16), dim3(128), 0, stream>>>(features, periods, period_emb, conv1_w, conv1_b, c1);
    k_frame2<<<dim3(32, 16), dim3(128), 0, stream>>>(c1, conv2_w, conv2_b, c2);
    k_fd<<<dim3(32, 16), dim3(128), 0, stream>>>(c2, fd1_w, fd1_b, fd2_w, fd2_b, cc);
    k_cpart<<<dim3(32, 16), dim3(192), 0, stream>>>(cc, grub_wih, grub_bih, cpart);
    k_init<<<dim3(1), dim3(128), 0, stream>>>(flags);
    k_gemm<<<dim3(1280, 18), dim3(256), 0, stream>>>(signals, signal_emb, cc, wihA, grua_bih, xp);
    k_serial<<<dim3(128), dim3(576), 0, stream>>>(grua_whh, grua_bhh, grub_wih, grub_whh, grub_bhh,
                                                  xp, cpart, gruA0, gruB0, hEx, flags, yB);
    k_fc<<<dim3(20480), dim3(256), 0, stream>>>(yB, fc1_w, fc1_b, fc2_w, fc2_b, alpha, beta, out);
}